// Round 7
// baseline (528.960 us; speedup 1.0000x reference)
//
#include <hip/hip_runtime.h>
#include <hip/hip_bf16.h>
#include <math.h>

#define B_   8
#define SQ_  256
#define SKV_ 1024
#define D_   1024
#define H_   16
#define DK_  64
#define DFF_ 4096

typedef __attribute__((ext_vector_type(4))) float f32x4;
typedef __attribute__((ext_vector_type(8))) __bf16 bf16x8;

__device__ __forceinline__ unsigned short f2bf(float f) {
    unsigned u = __builtin_bit_cast(unsigned, f);
    u += 0x7FFFu + ((u >> 16) & 1u);   // round-to-nearest-even
    return (unsigned short)(u >> 16);
}
__device__ __forceinline__ float bf2f(unsigned short h) {
    unsigned u = (unsigned)h << 16;
    return __builtin_bit_cast(float, u);
}

__device__ __forceinline__ void gload_lds16(const void* g, void* l) {
    __builtin_amdgcn_global_load_lds(
        (__attribute__((address_space(1))) void*)g,
        (__attribute__((address_space(3))) void*)l,
        16, 0, 0);
}

// ---------------------------------------------------------------------------
// 4x batched 1024x1024 weight transpose + fp32->bf16:  W[K][N] -> Wt[N][K]
// ---------------------------------------------------------------------------
__global__ __launch_bounds__(256) void transpose4_k(
    const float* __restrict__ Wa, const float* __restrict__ Wb,
    const float* __restrict__ Wc, const float* __restrict__ Wd,
    unsigned short* __restrict__ Ta, unsigned short* __restrict__ Tb,
    unsigned short* __restrict__ Tc, unsigned short* __restrict__ Td) {
    const float* Ws[4] = {Wa, Wb, Wc, Wd};
    unsigned short* Ts[4] = {Ta, Tb, Tc, Td};
    const float* W = Ws[blockIdx.z];
    unsigned short* Wt = Ts[blockIdx.z];
    __shared__ float t[32][33];
    const int n0 = blockIdx.x * 32, k0 = blockIdx.y * 32;
    const int tx = threadIdx.x, ty = threadIdx.y;
#pragma unroll
    for (int i = ty; i < 32; i += 8)
        t[i][tx] = W[(long)(k0 + i) * 1024 + n0 + tx];
    __syncthreads();
#pragma unroll
    for (int i = ty; i < 32; i += 8)
        Wt[(long)(n0 + i) * 1024 + k0 + tx] = f2bf(t[tx][i]);
}

__global__ __launch_bounds__(256) void transpose_cast_k(
    const float* __restrict__ W, unsigned short* __restrict__ Wt, int K, int N) {
    __shared__ float t[32][33];
    const int n0 = blockIdx.x * 32, k0 = blockIdx.y * 32;
    const int tx = threadIdx.x, ty = threadIdx.y;
#pragma unroll
    for (int i = ty; i < 32; i += 8)
        t[i][tx] = W[(long)(k0 + i) * N + n0 + tx];
    __syncthreads();
#pragma unroll
    for (int i = ty; i < 32; i += 8)
        Wt[(long)(n0 + i) * K + k0 + tx] = f2bf(t[tx][i]);
}

// ---------------------------------------------------------------------------
// Fused LayerNorm (row=1024 fp32) -> bf16
// ---------------------------------------------------------------------------
__global__ __launch_bounds__(256) void ln_k(
    const float* __restrict__ x, const float* __restrict__ g,
    const float* __restrict__ b, unsigned short* __restrict__ out) {
    const long row = blockIdx.x;
    const float4* xr = reinterpret_cast<const float4*>(x) + row * 256;
    const int t = threadIdx.x;
    float4 v = xr[t];
    __shared__ float sb[8];

    float s = v.x + v.y + v.z + v.w;
#pragma unroll
    for (int o = 1; o < 64; o <<= 1) s += __shfl_xor(s, o);
    if ((t & 63) == 0) sb[t >> 6] = s;
    __syncthreads();
    const float mu = (sb[0] + sb[1] + sb[2] + sb[3]) * (1.0f / 1024.0f);

    const float dx = v.x - mu, dy = v.y - mu, dz = v.z - mu, dw = v.w - mu;
    float q2 = dx * dx + dy * dy + dz * dz + dw * dw;
#pragma unroll
    for (int o = 1; o < 64; o <<= 1) q2 += __shfl_xor(q2, o);
    if ((t & 63) == 0) sb[4 + (t >> 6)] = q2;
    __syncthreads();
    const float var = (sb[4] + sb[5] + sb[6] + sb[7]) * (1.0f / 1024.0f);
    const float rs = rsqrtf(var + 1e-5f);

    const float4 gv = reinterpret_cast<const float4*>(g)[t];
    const float4 bv = reinterpret_cast<const float4*>(b)[t];
    ushort4 h4;
    h4.x = f2bf(dx * rs * gv.x + bv.x);
    h4.y = f2bf(dy * rs * gv.y + bv.y);
    h4.z = f2bf(dz * rs * gv.z + bv.z);
    h4.w = f2bf(dw * rs * gv.w + bv.w);
    reinterpret_cast<ushort4*>(out)[row * 256 + t] = h4;
}

// ---------------------------------------------------------------------------
// Fused attention middle (unchanged from round 6, verified passing)
// ---------------------------------------------------------------------------
#define ELD 1032
__global__ __launch_bounds__(512) void fattn_k(
    const unsigned short* __restrict__ Qh,   // [128][256][64]
    const unsigned short* __restrict__ Kh,   // [128][1024][64]
    const unsigned short* __restrict__ Vt,   // [128][64][1024]
    float* __restrict__ attn,                // [128][256][1024]
    unsigned short* __restrict__ ctx) {      // [8][256][1024]
    __shared__ unsigned short E_lds[64 * ELD];
    __shared__ unsigned short Q_lds[64 * 64];
    __shared__ unsigned short KV_lds[2][64 * 64];
    __shared__ float partial[8][64];
    __shared__ float invs_l[64];

    const int tid = threadIdx.x;
    const int wid = tid >> 6, lane = tid & 63;
    const int wr = wid >> 2, wc = wid & 3;
    const int r16 = lane & 15, kch = lane >> 4;
    const int z = blockIdx.x, qb = blockIdx.y;
    const int m0 = qb * 64;
    const long qoff = (long)z * (SQ_ * DK_) + (long)m0 * DK_;
    const long koff = (long)z * (SKV_ * DK_);
    const long voff = (long)z * (DK_ * SKV_);

    gload_lds16(Qh + qoff + tid * 8, &Q_lds[wid * 512]);
    gload_lds16(Kh + koff + tid * 8, &KV_lds[0][wid * 512]);
    __syncthreads();

    const f32x4 z4 = {0.f, 0.f, 0.f, 0.f};

    int cur = 0;
    for (int kt = 0; kt < 16; ++kt) {
        if (kt + 1 < 16)
            gload_lds16(Kh + koff + (kt + 1) * (64 * 64) + tid * 8,
                        &KV_lds[cur ^ 1][wid * 512]);
        f32x4 s[2] = {z4, z4};
        const int bro = (wc * 16 + r16) * 64;
#pragma unroll
        for (int k0 = 0; k0 < 64; k0 += 32) {
            const bf16x8 bfrag =
                *reinterpret_cast<const bf16x8*>(&KV_lds[cur][bro + k0 + kch * 8]);
#pragma unroll
            for (int fm = 0; fm < 2; ++fm) {
                const bf16x8 afrag = *reinterpret_cast<const bf16x8*>(
                    &Q_lds[(wr * 32 + fm * 16 + r16) * 64 + k0 + kch * 8]);
                s[fm] = __builtin_amdgcn_mfma_f32_16x16x32_bf16(afrag, bfrag, s[fm], 0, 0, 0);
            }
        }
#pragma unroll
        for (int fm = 0; fm < 2; ++fm)
#pragma unroll
            for (int j = 0; j < 4; ++j) {
                const int row = wr * 32 + fm * 16 + kch * 4 + j;
                const int col = kt * 64 + wc * 16 + r16;
                E_lds[row * ELD + col] = f2bf(__expf(s[fm][j] * 0.125f));
            }
        __syncthreads();
        cur ^= 1;
    }

    {
        const int r = tid & 63, c = tid >> 6;
        float s = 0.f;
        const unsigned* p = reinterpret_cast<const unsigned*>(&E_lds[r * ELD + c * 128]);
#pragma unroll
        for (int i = 0; i < 64; ++i) {
            const unsigned u = p[i];
            s += __builtin_bit_cast(float, u << 16) +
                 __builtin_bit_cast(float, u & 0xffff0000u);
        }
        partial[c][r] = s;
    }
    __syncthreads();
    if (tid < 64) {
        float t = 0.f;
#pragma unroll
        for (int c = 0; c < 8; ++c) t += partial[c][tid];
        invs_l[tid] = 1.0f / t;
    }
    __syncthreads();

    gload_lds16(Vt + voff + (tid >> 3) * SKV_ + (tid & 7) * 8, &KV_lds[0][wid * 512]);

    {
        float* abase = attn + (long)z * (SQ_ * SKV_) + (long)m0 * SKV_;
#pragma unroll
        for (int ro = 0; ro < 8; ++ro) {
            const int row = ro * 8 + wid;
            const float inv = invs_l[row];
#pragma unroll
            for (int cc = 0; cc < 4; ++cc) {
                const int col = cc * 256 + lane * 4;
                const ushort4 e4 =
                    *reinterpret_cast<const ushort4*>(&E_lds[row * ELD + col]);
                float4 o;
                o.x = bf2f(e4.x) * inv; o.y = bf2f(e4.y) * inv;
                o.z = bf2f(e4.z) * inv; o.w = bf2f(e4.w) * inv;
                reinterpret_cast<float4*>(abase + (long)row * SKV_)[col >> 2] = o;
            }
        }
    }
    __syncthreads();

    cur = 0;
    f32x4 acc[2] = {z4, z4};
    for (int kt = 0; kt < 16; ++kt) {
        if (kt + 1 < 16)
            gload_lds16(Vt + voff + (tid >> 3) * SKV_ + (kt + 1) * 64 + (tid & 7) * 8,
                        &KV_lds[cur ^ 1][wid * 512]);
        const int bro = (wc * 16 + r16) * 64;
#pragma unroll
        for (int k0 = 0; k0 < 64; k0 += 32) {
            const bf16x8 bfrag =
                *reinterpret_cast<const bf16x8*>(&KV_lds[cur][bro + k0 + kch * 8]);
#pragma unroll
            for (int fm = 0; fm < 2; ++fm) {
                const bf16x8 afrag = *reinterpret_cast<const bf16x8*>(
                    &E_lds[(wr * 32 + fm * 16 + r16) * ELD + kt * 64 + k0 + kch * 8]);
                acc[fm] = __builtin_amdgcn_mfma_f32_16x16x32_bf16(afrag, bfrag, acc[fm], 0, 0, 0);
            }
        }
        __syncthreads();
        cur ^= 1;
    }

    const int b = z >> 4, h = z & 15;
#pragma unroll
    for (int fm = 0; fm < 2; ++fm)
#pragma unroll
        for (int j = 0; j < 4; ++j) {
            const int row = wr * 32 + fm * 16 + kch * 4 + j;
            const int col = wc * 16 + r16;
            const float v = acc[fm][j] * invs_l[row];
            ctx[((long)(b * SQ_) + m0 + row) * D_ + h * 64 + col] = f2bf(v);
        }
}

// ---------------------------------------------------------------------------
// Split-K reduce for FFN2: out = sum_4(part) + bias + resid   (float4 grain)
// ---------------------------------------------------------------------------
__global__ __launch_bounds__(256) void reduce4_k(
    const float* __restrict__ part, const float* __restrict__ bias,
    const float* __restrict__ resid, float* __restrict__ out) {
    const long i4 = (long)blockIdx.x * 256 + threadIdx.x;
    const float4* p = reinterpret_cast<const float4*>(part);
    const float4 a = p[i4], b = p[i4 + 524288], c = p[i4 + 1048576],
                 d = p[i4 + 1572864];
    const float4 bb = reinterpret_cast<const float4*>(bias)[i4 & 255];
    const float4 r = reinterpret_cast<const float4*>(resid)[i4];
    float4 o;
    o.x = a.x + b.x + c.x + d.x + bb.x + r.x;
    o.y = a.y + b.y + c.y + d.y + bb.y + r.y;
    o.z = a.z + b.z + c.z + d.z + bb.z + r.z;
    o.w = a.w + b.w + c.w + d.w + bb.w + r.w;
    reinterpret_cast<float4*>(out)[i4] = o;
}

enum GemmMode {
    M_QSPLIT  = 0,  // bf16 out -> [b,h,sq,dk]   (+bias)
    M_KVSPLIT = 1,  // N=2048: n<1024 K->[b,h,skv,dk](+bias), else V->[b,h,dk,skv](+bias2)
    M_BIASF   = 2,  // fp32 out = acc + bias
    M_GELU    = 3,  // bf16 out = gelu(acc + bias)
    M_PART    = 4   // fp32 out = acc at z*sC + m*N + n  (split-K partial)
};

// ---------------------------------------------------------------------------
// 256x256 8-wave GEMM (T2 swizzle + T4 counted vmcnt + T5 setprio).
// BK=64, double-buffered 128KB LDS, tile-granularity depth-2 prefetch.
// Swizzle: logical<->physical LDS byte ^= ((byte>>7)&7)<<4 (involution);
// applied as inverse-swizzled global SOURCE (linear gload_lds dest) +
// swizzled ds_read address.
// ---------------------------------------------------------------------------
template <int MODE>
__global__ __launch_bounds__(512, 2) void gemm256_k(
    const unsigned short* __restrict__ A,
    const unsigned short* __restrict__ Bt,
    const float* __restrict__ bias,
    const float* __restrict__ bias2,
    float* __restrict__ outF,
    unsigned short* __restrict__ outH,
    int M, int N, int K, int lda, int ldb,
    long sA, long sB, long sC) {
    __shared__ unsigned short ldsA[2][256 * 64];   // 64 KB
    __shared__ unsigned short ldsB[2][256 * 64];   // 64 KB

    const int tid = threadIdx.x;
    const int wid = tid >> 6, lane = tid & 63;
    const int wr = wid >> 2, wc = wid & 3;         // 2 x 4 wave grid
    const int r16 = lane & 15, kch = lane >> 4;
    const int z = blockIdx.z;
    const long zA = (long)z * sA, zB = (long)z * sB;
    const int m0 = blockIdx.y * 256, n0 = blockIdx.x * 256;

    // stage K-tile kt (k0 = kt*64) into buffer p: 4+4 gload16 per thread.
    // Chunk c -> physical LDS byte c*16 (linear); data there belongs at
    // logical byte lb = pb ^ ((pb>>7)&7)<<4 -> (row, col).
    auto stage = [&](int p, int kt) {
        const int k0 = kt * 64;
#pragma unroll
        for (int i = 0; i < 4; ++i) {
            const int pb = (i * 512 + tid) * 16;
            const int lb = pb ^ (((pb >> 7) & 7) << 4);
            const int row = lb >> 7, col = (lb & 127) >> 1;
            gload_lds16(A + zA + (long)(m0 + row) * lda + (k0 + col),
                        &ldsA[p][(i * 512 + wid * 64) * 8]);
        }
#pragma unroll
        for (int i = 0; i < 4; ++i) {
            const int pb = (i * 512 + tid) * 16;
            const int lb = pb ^ (((pb >> 7) & 7) << 4);
            const int row = lb >> 7, col = (lb & 127) >> 1;
            gload_lds16(Bt + zB + (long)(n0 + row) * ldb + (k0 + col),
                        &ldsB[p][(i * 512 + wid * 64) * 8]);
        }
    };
    // swizzled ds_read of one bf16x8 fragment (logical row, k-sub kk)
    auto ldA = [&](int p, int row, int kk) {
        const int lb = row * 128 + kk * 64 + kch * 16;
        const int pb = lb ^ ((row & 7) << 4);
        return *reinterpret_cast<const bf16x8*>(
            reinterpret_cast<const char*>(&ldsA[p][0]) + pb);
    };
    auto ldB = [&](int p, int row, int kk) {
        const int lb = row * 128 + kk * 64 + kch * 16;
        const int pb = lb ^ ((row & 7) << 4);
        return *reinterpret_cast<const bf16x8*>(
            reinterpret_cast<const char*>(&ldsB[p][0]) + pb);
    };

    f32x4 acc[8][4];
#pragma unroll
    for (int i = 0; i < 8; ++i)
#pragma unroll
        for (int j = 0; j < 4; ++j) acc[i][j] = {0.f, 0.f, 0.f, 0.f};

    const int nK = K >> 6;
    stage(0, 0);
    stage(1, 1);

    for (int kt = 0; kt < nK; ++kt) {
        const int p = kt & 1;
        // counted wait: tile kt's 8 loads done; tile kt+1's 8 may stay in flight
        if (kt < nK - 1) asm volatile("s_waitcnt vmcnt(8)" ::: "memory");
        else             asm volatile("s_waitcnt vmcnt(0)" ::: "memory");
        __builtin_amdgcn_s_barrier();
        __builtin_amdgcn_sched_barrier(0);

        bf16x8 bfr[4][2];
#pragma unroll
        for (int fn = 0; fn < 4; ++fn) {
            bfr[fn][0] = ldB(p, wc * 64 + fn * 16 + r16, 0);
            bfr[fn][1] = ldB(p, wc * 64 + fn * 16 + r16, 1);
        }
#pragma unroll
        for (int q = 0; q < 4; ++q) {
            bf16x8 af[2][2];
#pragma unroll
            for (int i = 0; i < 2; ++i) {
                af[i][0] = ldA(p, wr * 128 + (2 * q + i) * 16 + r16, 0);
                af[i][1] = ldA(p, wr * 128 + (2 * q + i) * 16 + r16, 1);
            }
            __builtin_amdgcn_s_setprio(1);
#pragma unroll
            for (int i = 0; i < 2; ++i)
#pragma unroll
                for (int fn = 0; fn < 4; ++fn) {
                    acc[2 * q + i][fn] = __builtin_amdgcn_mfma_f32_16x16x32_bf16(
                        af[i][0], bfr[fn][0], acc[2 * q + i][fn], 0, 0, 0);
                    acc[2 * q + i][fn] = __builtin_amdgcn_mfma_f32_16x16x32_bf16(
                        af[i][1], bfr[fn][1], acc[2 * q + i][fn], 0, 0, 0);
                }
            __builtin_amdgcn_s_setprio(0);
            __builtin_amdgcn_s_barrier();   // phase boundary; q==3: read-done fence
        }
        __builtin_amdgcn_sched_barrier(0);
        if (kt + 2 < nK) stage(p, kt + 2);   // buffer p free; covered by next tile
    }

    // epilogue: gm = m0 + wr*128 + fm*16 + kch*4 + j ; gn = n0 + wc*64 + fn*16 + r16
#pragma unroll
    for (int fm = 0; fm < 8; ++fm) {
#pragma unroll
        for (int fn = 0; fn < 4; ++fn) {
            const int gn = n0 + wc * 64 + fn * 16 + r16;
            float bv = 0.0f;
            if constexpr (MODE == M_GELU) bv = bias[gn];
            if constexpr (MODE == M_KVSPLIT)
                bv = (gn < 1024) ? bias[gn] : bias2[gn - 1024];
#pragma unroll
            for (int j = 0; j < 4; ++j) {
                const int gm = m0 + wr * 128 + fm * 16 + kch * 4 + j;
                const float v = acc[fm][fn][j];
                if constexpr (MODE == M_KVSPLIT) {
                    const int bb = gm >> 10, ss = gm & 1023;
                    if (gn < 1024) {
                        const int hh = gn >> 6, dd = gn & 63;
                        outH[(((long)(bb * H_ + hh)) * SKV_ + ss) * DK_ + dd] = f2bf(v + bv);
                    } else {
                        const int gv = gn - 1024, hh = gv >> 6, dd = gv & 63;
                        outH[(size_t)8192 * 1024 +
                             (((long)(bb * H_ + hh)) * DK_ + dd) * SKV_ + ss] = f2bf(v + bv);
                    }
                } else if constexpr (MODE == M_GELU) {
                    const float u = v + bv;
                    outH[(long)gm * N + gn] =
                        f2bf(u * 0.5f * (1.0f + erff(u * 0.70710678f)));
                } else {  // M_PART
                    outF[(long)z * sC + (long)gm * N + gn] = v;
                }
            }
        }
    }
}

// ---------------------------------------------------------------------------
// m97-style 128-tile GEMM with 2-phase dbuf (kept for small shapes: Q, Wo)
// ---------------------------------------------------------------------------
template <int BM, int BN, int MODE>
__global__ __launch_bounds__(256, 2) void gemm_k(
    const unsigned short* __restrict__ A,
    const unsigned short* __restrict__ Bt,
    const float* __restrict__ bias,
    const float* __restrict__ bias2,
    float* __restrict__ outF,
    unsigned short* __restrict__ outH,
    int M, int N, int K, int lda, int ldb,
    long sA, long sB, long sC,
    float alpha) {
    constexpr int WM = BM / 2, WN = BN / 2;
    constexpr int FM = WM / 16, FN = WN / 16;
    __shared__ unsigned short ldsA[2][BM * 32];
    __shared__ unsigned short ldsB[2][BN * 32];

    const int tid = threadIdx.x;
    const int wid = tid >> 6, lane = tid & 63;
    const int wr = wid >> 1, wc = wid & 1;
    const int r16 = lane & 15, kch = lane >> 4;
    const int z = blockIdx.z;
    const long zA = (long)z * sA, zB = (long)z * sB;
    const int m0 = blockIdx.y * BM, n0 = blockIdx.x * BN;

    auto stage = [&](int buf, int kt) {
        const int k0 = kt * 32;
#pragma unroll
        for (int j = 0; j < BM / 64; ++j) {
            const int e = (j * 256 + tid) * 8, rr = e >> 5, cc = e & 31;
            gload_lds16(A + zA + (long)(m0 + rr) * lda + (k0 + cc),
                        &ldsA[buf][(j * 256 + wid * 64) * 8]);
        }
#pragma unroll
        for (int j = 0; j < BN / 64; ++j) {
            const int e = (j * 256 + tid) * 8, rr = e >> 5, cc = e & 31;
            gload_lds16(Bt + zB + (long)(n0 + rr) * ldb + (k0 + cc),
                        &ldsB[buf][(j * 256 + wid * 64) * 8]);
        }
    };

    const f32x4 zero4 = {0.f, 0.f, 0.f, 0.f};
    f32x4 acc[FM][FN];
#pragma unroll
    for (int i = 0; i < FM; ++i)
#pragma unroll
        for (int j = 0; j < FN; ++j) acc[i][j] = zero4;

    const int nK = K / 32;
    stage(0, 0);
    __syncthreads();
    int cur = 0;
    for (int kt = 0; kt < nK; ++kt) {
        if (kt + 1 < nK) stage(cur ^ 1, kt + 1);

        bf16x8 af[FM], bfr[FN];
#pragma unroll
        for (int fm = 0; fm < FM; ++fm)
            af[fm] = *reinterpret_cast<const bf16x8*>(
                &ldsA[cur][(wr * WM + fm * 16 + r16) * 32 + kch * 8]);
#pragma unroll
        for (int fn = 0; fn < FN; ++fn)
            bfr[fn] = *reinterpret_cast<const bf16x8*>(
                &ldsB[cur][(wc * WN + fn * 16 + r16) * 32 + kch * 8]);
#pragma unroll
        for (int fm = 0; fm < FM; ++fm)
#pragma unroll
            for (int fn = 0; fn < FN; ++fn)
                acc[fm][fn] = __builtin_amdgcn_mfma_f32_16x16x32_bf16(
                    af[fm], bfr[fn], acc[fm][fn], 0, 0, 0);
        __syncthreads();
        cur ^= 1;
    }

#pragma unroll
    for (int fm = 0; fm < FM; ++fm) {
#pragma unroll
        for (int fn = 0; fn < FN; ++fn) {
            const int gn = n0 + wc * WN + fn * 16 + r16;
            float bv = 0.0f;
            if constexpr (MODE == M_QSPLIT || MODE == M_BIASF) bv = bias[gn];
#pragma unroll
            for (int j = 0; j < 4; ++j) {
                const int gm = m0 + wr * WM + fm * 16 + kch * 4 + j;
                const float v = acc[fm][fn][j];
                if constexpr (MODE == M_QSPLIT) {
                    const int bb = gm >> 8, ss = gm & 255, hh = gn >> 6, dd = gn & 63;
                    outH[(((long)(bb * H_ + hh)) * SQ_ + ss) * DK_ + dd] = f2bf(v + bv);
                } else if constexpr (MODE == M_BIASF) {
                    outF[(long)gm * N + gn] = v + bv;
                }
            }
        }
    }
    (void)alpha; (void)bias2;
}

// ---------------------------------------------------------------------------
extern "C" void kernel_launch(void* const* d_in, const int* in_sizes, int n_in,
                              void* d_out, int out_size, void* d_ws, size_t ws_size,
                              hipStream_t stream) {
    (void)in_sizes; (void)n_in; (void)out_size; (void)ws_size;
    const float* memory = (const float*)d_in[0];
    const float* q      = (const float*)d_in[1];
    const float* Wq = (const float*)d_in[2];  const float* bq = (const float*)d_in[3];
    const float* Wk = (const float*)d_in[4];  const float* bk = (const float*)d_in[5];
    const float* Wv = (const float*)d_in[6];  const float* bv = (const float*)d_in[7];
    const float* Wo = (const float*)d_in[8];  const float* bo = (const float*)d_in[9];
    const float* g_kv = (const float*)d_in[10]; const float* b_kv = (const float*)d_in[11];
    const float* g_q  = (const float*)d_in[12]; const float* b_q  = (const float*)d_in[13];
    const float* g_ff = (const float*)d_in[14]; const float* b_ff = (const float*)d_in[15];
    const float* W1 = (const float*)d_in[16]; const float* b1 = (const float*)d_in[17];
    const float* W2 = (const float*)d_in[18]; const float* b2 = (const float*)d_in[19];

    float* outO = (float*)d_out;                       // [2048,1024] fp32
    float* outA = outO + (size_t)2048 * 1024;          // [128,256,1024] fp32 attn

    char* w = (char*)d_ws;
    unsigned short* kvB  = (unsigned short*)w; w += (size_t)8192 * 1024 * 2;
    unsigned short* qB   = (unsigned short*)w; w += (size_t)2048 * 1024 * 2;
    unsigned short* WqT  = (unsigned short*)w; w += (size_t)1024 * 1024 * 2;
    unsigned short* WkvT = (unsigned short*)w; w += (size_t)2048 * 1024 * 2;  // [Wk;Wv]^T
    unsigned short* WoT  = (unsigned short*)w; w += (size_t)1024 * 1024 * 2;
    unsigned short* W1T  = (unsigned short*)w; w += (size_t)4096 * 1024 * 2;
    unsigned short* W2T  = (unsigned short*)w; w += (size_t)1024 * 4096 * 2;
    unsigned short* Qh   = (unsigned short*)w; w += (size_t)2048 * 1024 * 2;  // [b,h,256,64]
    unsigned short* KVh  = (unsigned short*)w; w += (size_t)16384 * 1024 * 2; // Kh then Vt
    unsigned short* ctxB = (unsigned short*)w; w += (size_t)2048 * 1024 * 2;  // [b,sq,D]
    float*          xF   = (float*)w;          w += (size_t)2048 * 1024 * 4;  // attn out fp32
    unsigned short* yB   = (unsigned short*)w; w += (size_t)2048 * 1024 * 2;  // LN(x) bf16
    unsigned short* h1B  = (unsigned short*)w; w += (size_t)2048 * 4096 * 2;  // gelu(FFN1)
    float*          part = (float*)w;          w += (size_t)4 * 2048 * 1024 * 4; // split-K

    unsigned short* Kh = KVh;                          // [b,h,1024,64]
    unsigned short* Vt = KVh + (size_t)8192 * 1024;    // [b,h,64,1024]

    const dim3 blk(256);
    transpose4_k<<<dim3(32, 32, 4), dim3(32, 8), 0, stream>>>(
        Wq, Wk, Wv, Wo, WqT, WkvT, WkvT + (size_t)1024 * 1024, WoT);
    transpose_cast_k<<<dim3(128, 32), dim3(32, 8), 0, stream>>>(W1, W1T, 1024, 4096);
    transpose_cast_k<<<dim3(32, 128), dim3(32, 8), 0, stream>>>(W2, W2T, 4096, 1024);

    ln_k<<<8192, blk, 0, stream>>>(memory, g_kv, b_kv, kvB);
    ln_k<<<2048, blk, 0, stream>>>(q, g_q, b_q, qB);

    // Q projection (small; 2-phase 128-tile)
    gemm_k<64, 128, M_QSPLIT><<<dim3(8, 32, 1), blk, 0, stream>>>(
        qB, WqT, bq, nullptr, nullptr, Qh, 2048, 1024, 1024, 1024, 1024, 0, 0, 0, 1.f);
    // fused K+V projection: 256x256 8-phase-style (32x8 = 256 wgs)
    gemm256_k<M_KVSPLIT><<<dim3(8, 32, 1), dim3(512), 0, stream>>>(
        kvB, WkvT, bk, bv, nullptr, KVh, 8192, 2048, 1024, 1024, 1024, 0, 0, 0);

    // fused attention middle
    fattn_k<<<dim3(128, 4), dim3(512), 0, stream>>>(Qh, Kh, Vt, outA, ctxB);

    // x = ctx @ Wo + bo
    gemm_k<64, 128, M_BIASF><<<dim3(8, 32, 1), blk, 0, stream>>>(
        ctxB, WoT, bo, nullptr, xF, nullptr, 2048, 1024, 1024, 1024, 1024, 0, 0, 0, 1.f);

    ln_k<<<2048, blk, 0, stream>>>(xF, g_ff, b_ff, yB);

    // h1 = gelu(y @ W1 + b1): 256-tile (16x8 = 128 wgs)
    gemm256_k<M_GELU><<<dim3(16, 8, 1), dim3(512), 0, stream>>>(
        yB, W1T, b1, nullptr, nullptr, h1B, 2048, 4096, 1024, 1024, 1024, 0, 0, 0);

    // FFN2 split-K x4 partials: 256-tile (4x8x4 = 128 wgs)
    gemm256_k<M_PART><<<dim3(4, 8, 4), dim3(512), 0, stream>>>(
        h1B, W2T, nullptr, nullptr, part, nullptr, 2048, 1024, 1024, 4096, 4096,
        1024, 1024, (long)2048 * 1024);
    reduce4_k<<<2048, blk, 0, stream>>>(part, b2, xF, outO);
}

// Round 8
// 518.167 us; speedup vs baseline: 1.0208x; 1.0208x over previous
//
#include <hip/hip_runtime.h>
#include <hip/hip_bf16.h>
#include <math.h>

#define B_   8
#define SQ_  256
#define SKV_ 1024
#define D_   1024
#define H_   16
#define DK_  64
#define DFF_ 4096

typedef __attribute__((ext_vector_type(4))) float f32x4;
typedef __attribute__((ext_vector_type(8))) __bf16 bf16x8;

__device__ __forceinline__ unsigned short f2bf(float f) {
    unsigned u = __builtin_bit_cast(unsigned, f);
    u += 0x7FFFu + ((u >> 16) & 1u);   // round-to-nearest-even
    return (unsigned short)(u >> 16);
}
__device__ __forceinline__ float bf2f(unsigned short h) {
    unsigned u = (unsigned)h << 16;
    return __builtin_bit_cast(float, u);
}

__device__ __forceinline__ void gload_lds16(const void* g, void* l) {
    __builtin_amdgcn_global_load_lds(
        (__attribute__((address_space(1))) void*)g,
        (__attribute__((address_space(3))) void*)l,
        16, 0, 0);
}

// ---------------------------------------------------------------------------
// 4x batched 1024x1024 weight transpose + fp32->bf16:  W[K][N] -> Wt[N][K]
// ---------------------------------------------------------------------------
__global__ __launch_bounds__(256) void transpose4_k(
    const float* __restrict__ Wa, const float* __restrict__ Wb,
    const float* __restrict__ Wc, const float* __restrict__ Wd,
    unsigned short* __restrict__ Ta, unsigned short* __restrict__ Tb,
    unsigned short* __restrict__ Tc, unsigned short* __restrict__ Td) {
    const float* Ws[4] = {Wa, Wb, Wc, Wd};
    unsigned short* Ts[4] = {Ta, Tb, Tc, Td};
    const float* W = Ws[blockIdx.z];
    unsigned short* Wt = Ts[blockIdx.z];
    __shared__ float t[32][33];
    const int n0 = blockIdx.x * 32, k0 = blockIdx.y * 32;
    const int tx = threadIdx.x, ty = threadIdx.y;
#pragma unroll
    for (int i = ty; i < 32; i += 8)
        t[i][tx] = W[(long)(k0 + i) * 1024 + n0 + tx];
    __syncthreads();
#pragma unroll
    for (int i = ty; i < 32; i += 8)
        Wt[(long)(n0 + i) * 1024 + k0 + tx] = f2bf(t[tx][i]);
}

__global__ __launch_bounds__(256) void transpose_cast_k(
    const float* __restrict__ W, unsigned short* __restrict__ Wt, int K, int N) {
    __shared__ float t[32][33];
    const int n0 = blockIdx.x * 32, k0 = blockIdx.y * 32;
    const int tx = threadIdx.x, ty = threadIdx.y;
#pragma unroll
    for (int i = ty; i < 32; i += 8)
        t[i][tx] = W[(long)(k0 + i) * N + n0 + tx];
    __syncthreads();
#pragma unroll
    for (int i = ty; i < 32; i += 8)
        Wt[(long)(n0 + i) * K + k0 + tx] = f2bf(t[tx][i]);
}

// ---------------------------------------------------------------------------
// Fused LayerNorm (row=1024 fp32) -> bf16
// ---------------------------------------------------------------------------
__global__ __launch_bounds__(256) void ln_k(
    const float* __restrict__ x, const float* __restrict__ g,
    const float* __restrict__ b, unsigned short* __restrict__ out) {
    const long row = blockIdx.x;
    const float4* xr = reinterpret_cast<const float4*>(x) + row * 256;
    const int t = threadIdx.x;
    float4 v = xr[t];
    __shared__ float sb[8];

    float s = v.x + v.y + v.z + v.w;
#pragma unroll
    for (int o = 1; o < 64; o <<= 1) s += __shfl_xor(s, o);
    if ((t & 63) == 0) sb[t >> 6] = s;
    __syncthreads();
    const float mu = (sb[0] + sb[1] + sb[2] + sb[3]) * (1.0f / 1024.0f);

    const float dx = v.x - mu, dy = v.y - mu, dz = v.z - mu, dw = v.w - mu;
    float q2 = dx * dx + dy * dy + dz * dz + dw * dw;
#pragma unroll
    for (int o = 1; o < 64; o <<= 1) q2 += __shfl_xor(q2, o);
    if ((t & 63) == 0) sb[4 + (t >> 6)] = q2;
    __syncthreads();
    const float var = (sb[4] + sb[5] + sb[6] + sb[7]) * (1.0f / 1024.0f);
    const float rs = rsqrtf(var + 1e-5f);

    const float4 gv = reinterpret_cast<const float4*>(g)[t];
    const float4 bv = reinterpret_cast<const float4*>(b)[t];
    ushort4 h4;
    h4.x = f2bf(dx * rs * gv.x + bv.x);
    h4.y = f2bf(dy * rs * gv.y + bv.y);
    h4.z = f2bf(dz * rs * gv.z + bv.z);
    h4.w = f2bf(dw * rs * gv.w + bv.w);
    reinterpret_cast<ushort4*>(out)[row * 256 + t] = h4;
}

// ---------------------------------------------------------------------------
// Fused attention middle (unchanged, verified passing)
// ---------------------------------------------------------------------------
#define ELD 1032
__global__ __launch_bounds__(512) void fattn_k(
    const unsigned short* __restrict__ Qh,   // [128][256][64]
    const unsigned short* __restrict__ Kh,   // [128][1024][64]
    const unsigned short* __restrict__ Vt,   // [128][64][1024]
    float* __restrict__ attn,                // [128][256][1024]
    unsigned short* __restrict__ ctx) {      // [8][256][1024]
    __shared__ unsigned short E_lds[64 * ELD];
    __shared__ unsigned short Q_lds[64 * 64];
    __shared__ unsigned short KV_lds[2][64 * 64];
    __shared__ float partial[8][64];
    __shared__ float invs_l[64];

    const int tid = threadIdx.x;
    const int wid = tid >> 6, lane = tid & 63;
    const int wr = wid >> 2, wc = wid & 3;
    const int r16 = lane & 15, kch = lane >> 4;
    const int z = blockIdx.x, qb = blockIdx.y;
    const int m0 = qb * 64;
    const long qoff = (long)z * (SQ_ * DK_) + (long)m0 * DK_;
    const long koff = (long)z * (SKV_ * DK_);
    const long voff = (long)z * (DK_ * SKV_);

    gload_lds16(Qh + qoff + tid * 8, &Q_lds[wid * 512]);
    gload_lds16(Kh + koff + tid * 8, &KV_lds[0][wid * 512]);
    __syncthreads();

    const f32x4 z4 = {0.f, 0.f, 0.f, 0.f};

    int cur = 0;
    for (int kt = 0; kt < 16; ++kt) {
        if (kt + 1 < 16)
            gload_lds16(Kh + koff + (kt + 1) * (64 * 64) + tid * 8,
                        &KV_lds[cur ^ 1][wid * 512]);
        f32x4 s[2] = {z4, z4};
        const int bro = (wc * 16 + r16) * 64;
#pragma unroll
        for (int k0 = 0; k0 < 64; k0 += 32) {
            const bf16x8 bfrag =
                *reinterpret_cast<const bf16x8*>(&KV_lds[cur][bro + k0 + kch * 8]);
#pragma unroll
            for (int fm = 0; fm < 2; ++fm) {
                const bf16x8 afrag = *reinterpret_cast<const bf16x8*>(
                    &Q_lds[(wr * 32 + fm * 16 + r16) * 64 + k0 + kch * 8]);
                s[fm] = __builtin_amdgcn_mfma_f32_16x16x32_bf16(afrag, bfrag, s[fm], 0, 0, 0);
            }
        }
#pragma unroll
        for (int fm = 0; fm < 2; ++fm)
#pragma unroll
            for (int j = 0; j < 4; ++j) {
                const int row = wr * 32 + fm * 16 + kch * 4 + j;
                const int col = kt * 64 + wc * 16 + r16;
                E_lds[row * ELD + col] = f2bf(__expf(s[fm][j] * 0.125f));
            }
        __syncthreads();
        cur ^= 1;
    }

    {
        const int r = tid & 63, c = tid >> 6;
        float s = 0.f;
        const unsigned* p = reinterpret_cast<const unsigned*>(&E_lds[r * ELD + c * 128]);
#pragma unroll
        for (int i = 0; i < 64; ++i) {
            const unsigned u = p[i];
            s += __builtin_bit_cast(float, u << 16) +
                 __builtin_bit_cast(float, u & 0xffff0000u);
        }
        partial[c][r] = s;
    }
    __syncthreads();
    if (tid < 64) {
        float t = 0.f;
#pragma unroll
        for (int c = 0; c < 8; ++c) t += partial[c][tid];
        invs_l[tid] = 1.0f / t;
    }
    __syncthreads();

    gload_lds16(Vt + voff + (tid >> 3) * SKV_ + (tid & 7) * 8, &KV_lds[0][wid * 512]);

    {
        float* abase = attn + (long)z * (SQ_ * SKV_) + (long)m0 * SKV_;
#pragma unroll
        for (int ro = 0; ro < 8; ++ro) {
            const int row = ro * 8 + wid;
            const float inv = invs_l[row];
#pragma unroll
            for (int cc = 0; cc < 4; ++cc) {
                const int col = cc * 256 + lane * 4;
                const ushort4 e4 =
                    *reinterpret_cast<const ushort4*>(&E_lds[row * ELD + col]);
                float4 o;
                o.x = bf2f(e4.x) * inv; o.y = bf2f(e4.y) * inv;
                o.z = bf2f(e4.z) * inv; o.w = bf2f(e4.w) * inv;
                reinterpret_cast<float4*>(abase + (long)row * SKV_)[col >> 2] = o;
            }
        }
    }
    __syncthreads();

    cur = 0;
    f32x4 acc[2] = {z4, z4};
    for (int kt = 0; kt < 16; ++kt) {
        if (kt + 1 < 16)
            gload_lds16(Vt + voff + (tid >> 3) * SKV_ + (kt + 1) * 64 + (tid & 7) * 8,
                        &KV_lds[cur ^ 1][wid * 512]);
        const int bro = (wc * 16 + r16) * 64;
#pragma unroll
        for (int k0 = 0; k0 < 64; k0 += 32) {
            const bf16x8 bfrag =
                *reinterpret_cast<const bf16x8*>(&KV_lds[cur][bro + k0 + kch * 8]);
#pragma unroll
            for (int fm = 0; fm < 2; ++fm) {
                const bf16x8 afrag = *reinterpret_cast<const bf16x8*>(
                    &E_lds[(wr * 32 + fm * 16 + r16) * ELD + kt * 64 + k0 + kch * 8]);
                acc[fm] = __builtin_amdgcn_mfma_f32_16x16x32_bf16(afrag, bfrag, acc[fm], 0, 0, 0);
            }
        }
        __syncthreads();
        cur ^= 1;
    }

    const int b = z >> 4, h = z & 15;
#pragma unroll
    for (int fm = 0; fm < 2; ++fm)
#pragma unroll
        for (int j = 0; j < 4; ++j) {
            const int row = wr * 32 + fm * 16 + kch * 4 + j;
            const int col = wc * 16 + r16;
            const float v = acc[fm][j] * invs_l[row];
            ctx[((long)(b * SQ_) + m0 + row) * D_ + h * 64 + col] = f2bf(v);
        }
}

// ---------------------------------------------------------------------------
// Split-K(2) reduce for FFN2: out = part0 + part1 + bias + resid
// ---------------------------------------------------------------------------
__global__ __launch_bounds__(256) void reduce2_k(
    const float* __restrict__ part, const float* __restrict__ bias,
    const float* __restrict__ resid, float* __restrict__ out) {
    const long i4 = (long)blockIdx.x * 256 + threadIdx.x;
    const float4* p = reinterpret_cast<const float4*>(part);
    const float4 a = p[i4], b = p[i4 + 524288];
    const float4 bb = reinterpret_cast<const float4*>(bias)[i4 & 255];
    const float4 r = reinterpret_cast<const float4*>(resid)[i4];
    float4 o;
    o.x = a.x + b.x + bb.x + r.x;
    o.y = a.y + b.y + bb.y + r.y;
    o.z = a.z + b.z + bb.z + r.z;
    o.w = a.w + b.w + bb.w + r.w;
    reinterpret_cast<float4*>(out)[i4] = o;
}

// ---------------------------------------------------------------------------
// bf16 GEMM, m97 structure + double-buffered LDS prefetch. 64x128 tiles for
// the big GEMMs: operands are L3-resident, so small tiles multiply L2 reads
// (cheap) and buy TLP for a latency-bound regime (6 blocks/CU by LDS).
// ---------------------------------------------------------------------------
enum GemmMode {
    M_QSPLIT  = 0,  // bf16 out -> [b,h,sq,dk]   (+bias)
    M_KVSPLIT = 1,  // N=2048: n<1024 K->[b,h,skv,dk](+bias), else V->[b,h,dk,skv](+bias2)
    M_BIASF   = 2,  // fp32 out = acc + bias
    M_GELU    = 3,  // bf16 out = gelu(acc + bias)
    M_PART    = 4   // fp32 out = acc at z*sC + m*N + n  (split-K partial, A/B k-offset by z)
};

template <int BM, int BN, int MODE>
__global__ __launch_bounds__(256, 2) void gemm_k(
    const unsigned short* __restrict__ A,
    const unsigned short* __restrict__ Bt,
    const float* __restrict__ bias,
    const float* __restrict__ bias2,
    float* __restrict__ outF,
    unsigned short* __restrict__ outH,
    int M, int N, int K, int lda, int ldb,
    long sA, long sB, long sC,
    float alpha) {
    constexpr int WM = BM / 2, WN = BN / 2;
    constexpr int FM = WM / 16, FN = WN / 16;
    __shared__ unsigned short ldsA[2][BM * 32];
    __shared__ unsigned short ldsB[2][BN * 32];

    const int tid = threadIdx.x;
    const int wid = tid >> 6, lane = tid & 63;
    const int wr = wid >> 1, wc = wid & 1;
    const int r16 = lane & 15, kch = lane >> 4;
    const int z = blockIdx.z;
    const long zA = (long)z * sA, zB = (long)z * sB;
    const int m0 = blockIdx.y * BM, n0 = blockIdx.x * BN;

    auto stage = [&](int buf, int kt) {
        const int k0 = kt * 32;
#pragma unroll
        for (int j = 0; j < BM / 64; ++j) {
            const int e = (j * 256 + tid) * 8, rr = e >> 5, cc = e & 31;
            gload_lds16(A + zA + (long)(m0 + rr) * lda + (k0 + cc),
                        &ldsA[buf][(j * 256 + wid * 64) * 8]);
        }
#pragma unroll
        for (int j = 0; j < BN / 64; ++j) {
            const int e = (j * 256 + tid) * 8, rr = e >> 5, cc = e & 31;
            gload_lds16(Bt + zB + (long)(n0 + rr) * ldb + (k0 + cc),
                        &ldsB[buf][(j * 256 + wid * 64) * 8]);
        }
    };

    const f32x4 zero4 = {0.f, 0.f, 0.f, 0.f};
    f32x4 acc[FM][FN];
#pragma unroll
    for (int i = 0; i < FM; ++i)
#pragma unroll
        for (int j = 0; j < FN; ++j) acc[i][j] = zero4;

    const int nK = K / 32;
    stage(0, 0);
    __syncthreads();
    int cur = 0;
    for (int kt = 0; kt < nK; ++kt) {
        if (kt + 1 < nK) stage(cur ^ 1, kt + 1);   // prefetch flies under MFMA

        bf16x8 af[FM], bfr[FN];
#pragma unroll
        for (int fm = 0; fm < FM; ++fm)
            af[fm] = *reinterpret_cast<const bf16x8*>(
                &ldsA[cur][(wr * WM + fm * 16 + r16) * 32 + kch * 8]);
#pragma unroll
        for (int fn = 0; fn < FN; ++fn)
            bfr[fn] = *reinterpret_cast<const bf16x8*>(
                &ldsB[cur][(wc * WN + fn * 16 + r16) * 32 + kch * 8]);
#pragma unroll
        for (int fm = 0; fm < FM; ++fm)
#pragma unroll
            for (int fn = 0; fn < FN; ++fn)
                acc[fm][fn] = __builtin_amdgcn_mfma_f32_16x16x32_bf16(
                    af[fm], bfr[fn], acc[fm][fn], 0, 0, 0);
        __syncthreads();
        cur ^= 1;
    }

    // epilogue: D row = kch*4 + j, col = r16
#pragma unroll
    for (int fm = 0; fm < FM; ++fm) {
#pragma unroll
        for (int fn = 0; fn < FN; ++fn) {
            const int gn = n0 + wc * WN + fn * 16 + r16;
            float bv = 0.0f;
            if constexpr (MODE == M_QSPLIT || MODE == M_BIASF || MODE == M_GELU)
                bv = bias[gn];
            if constexpr (MODE == M_KVSPLIT)
                bv = (gn < 1024) ? bias[gn] : bias2[gn - 1024];
#pragma unroll
            for (int j = 0; j < 4; ++j) {
                const int gm = m0 + wr * WM + fm * 16 + kch * 4 + j;
                const float v = acc[fm][fn][j];
                if constexpr (MODE == M_QSPLIT) {
                    const int bb = gm >> 8, ss = gm & 255, hh = gn >> 6, dd = gn & 63;
                    outH[(((long)(bb * H_ + hh)) * SQ_ + ss) * DK_ + dd] = f2bf(v + bv);
                } else if constexpr (MODE == M_KVSPLIT) {
                    const int bb = gm >> 10, ss = gm & 1023;
                    if (gn < 1024) {
                        const int hh = gn >> 6, dd = gn & 63;
                        outH[(((long)(bb * H_ + hh)) * SKV_ + ss) * DK_ + dd] = f2bf(v + bv);
                    } else {
                        const int gv = gn - 1024, hh = gv >> 6, dd = gv & 63;
                        outH[(size_t)8192 * 1024 +
                             (((long)(bb * H_ + hh)) * DK_ + dd) * SKV_ + ss] = f2bf(v + bv);
                    }
                } else if constexpr (MODE == M_BIASF) {
                    outF[(long)gm * N + gn] = v + bv;
                } else if constexpr (MODE == M_GELU) {
                    const float u = v + bv;
                    outH[(long)gm * N + gn] =
                        f2bf(u * 0.5f * (1.0f + erff(u * 0.70710678f)));
                } else {  // M_PART
                    outF[(long)z * sC + (long)gm * N + gn] = v;
                }
            }
        }
    }
    (void)alpha;
}

// ---------------------------------------------------------------------------
extern "C" void kernel_launch(void* const* d_in, const int* in_sizes, int n_in,
                              void* d_out, int out_size, void* d_ws, size_t ws_size,
                              hipStream_t stream) {
    (void)in_sizes; (void)n_in; (void)out_size; (void)ws_size;
    const float* memory = (const float*)d_in[0];
    const float* q      = (const float*)d_in[1];
    const float* Wq = (const float*)d_in[2];  const float* bq = (const float*)d_in[3];
    const float* Wk = (const float*)d_in[4];  const float* bk = (const float*)d_in[5];
    const float* Wv = (const float*)d_in[6];  const float* bv = (const float*)d_in[7];
    const float* Wo = (const float*)d_in[8];  const float* bo = (const float*)d_in[9];
    const float* g_kv = (const float*)d_in[10]; const float* b_kv = (const float*)d_in[11];
    const float* g_q  = (const float*)d_in[12]; const float* b_q  = (const float*)d_in[13];
    const float* g_ff = (const float*)d_in[14]; const float* b_ff = (const float*)d_in[15];
    const float* W1 = (const float*)d_in[16]; const float* b1 = (const float*)d_in[17];
    const float* W2 = (const float*)d_in[18]; const float* b2 = (const float*)d_in[19];

    float* outO = (float*)d_out;                       // [2048,1024] fp32
    float* outA = outO + (size_t)2048 * 1024;          // [128,256,1024] fp32 attn

    char* w = (char*)d_ws;
    unsigned short* kvB  = (unsigned short*)w; w += (size_t)8192 * 1024 * 2;
    unsigned short* qB   = (unsigned short*)w; w += (size_t)2048 * 1024 * 2;
    unsigned short* WqT  = (unsigned short*)w; w += (size_t)1024 * 1024 * 2;
    unsigned short* WkvT = (unsigned short*)w; w += (size_t)2048 * 1024 * 2;  // [Wk;Wv]^T
    unsigned short* WoT  = (unsigned short*)w; w += (size_t)1024 * 1024 * 2;
    unsigned short* W1T  = (unsigned short*)w; w += (size_t)4096 * 1024 * 2;
    unsigned short* W2T  = (unsigned short*)w; w += (size_t)1024 * 4096 * 2;
    unsigned short* Qh   = (unsigned short*)w; w += (size_t)2048 * 1024 * 2;  // [b,h,256,64]
    unsigned short* KVh  = (unsigned short*)w; w += (size_t)16384 * 1024 * 2; // Kh then Vt
    unsigned short* ctxB = (unsigned short*)w; w += (size_t)2048 * 1024 * 2;  // [b,sq,D]
    float*          xF   = (float*)w;          w += (size_t)2048 * 1024 * 4;  // attn out fp32
    unsigned short* yB   = (unsigned short*)w; w += (size_t)2048 * 1024 * 2;  // LN(x) bf16
    unsigned short* h1B  = (unsigned short*)w; w += (size_t)2048 * 4096 * 2;  // gelu(FFN1)
    float*          part = (float*)w;          w += (size_t)2 * 2048 * 1024 * 4; // split-K(2)

    unsigned short* Kh = KVh;                          // [b,h,1024,64]
    unsigned short* Vt = KVh + (size_t)8192 * 1024;    // [b,h,64,1024]

    const dim3 blk(256);
    transpose4_k<<<dim3(32, 32, 4), dim3(32, 8), 0, stream>>>(
        Wq, Wk, Wv, Wo, WqT, WkvT, WkvT + (size_t)1024 * 1024, WoT);
    transpose_cast_k<<<dim3(128, 32), dim3(32, 8), 0, stream>>>(W1, W1T, 1024, 4096);
    transpose_cast_k<<<dim3(32, 128), dim3(32, 8), 0, stream>>>(W2, W2T, 4096, 1024);

    ln_k<<<8192, blk, 0, stream>>>(memory, g_kv, b_kv, kvB);
    ln_k<<<2048, blk, 0, stream>>>(q, g_q, b_q, qB);

    // Q projection (64x128 -> 256 wgs)
    gemm_k<64, 128, M_QSPLIT><<<dim3(8, 32, 1), blk, 0, stream>>>(
        qB, WqT, bq, nullptr, nullptr, Qh, 2048, 1024, 1024, 1024, 1024, 0, 0, 0, 1.f);
    // fused K+V projection (64x128 -> 2048 wgs; operands L3-resident)
    gemm_k<64, 128, M_KVSPLIT><<<dim3(16, 128, 1), blk, 0, stream>>>(
        kvB, WkvT, bk, bv, nullptr, KVh, 8192, 2048, 1024, 1024, 1024, 0, 0, 0, 1.f);

    // fused attention middle
    fattn_k<<<dim3(128, 4), dim3(512), 0, stream>>>(Qh, Kh, Vt, outA, ctxB);

    // x = ctx @ Wo + bo
    gemm_k<64, 128, M_BIASF><<<dim3(8, 32, 1), blk, 0, stream>>>(
        ctxB, WoT, bo, nullptr, xF, nullptr, 2048, 1024, 1024, 1024, 1024, 0, 0, 0, 1.f);

    ln_k<<<2048, blk, 0, stream>>>(xF, g_ff, b_ff, yB);

    // h1 = gelu(y @ W1 + b1)  (64x128 -> 1024 wgs)
    gemm_k<64, 128, M_GELU><<<dim3(32, 32, 1), blk, 0, stream>>>(
        yB, W1T, b1, nullptr, nullptr, h1B, 2048, 4096, 1024, 1024, 1024, 0, 0, 0, 1.f);

    // FFN2 split-K x2 partials (64x128, K=2048 each -> 512 wgs), then reduce
    gemm_k<64, 128, M_PART><<<dim3(8, 32, 2), blk, 0, stream>>>(
        h1B, W2T, nullptr, nullptr, part, nullptr, 2048, 1024, 2048, 4096, 4096,
        2048, 2048, (long)2048 * 1024, 1.f);
    reduce2_k<<<2048, blk, 0, stream>>>(part, b2, xF, outO);
}